// Round 4
// baseline (669.284 us; speedup 1.0000x reference)
//
#include <hip/hip_runtime.h>

#define NN 50000
#define EE 800000
#define DD 64
#define GG 512
#define TILES 782          // ceil(NN/64)
#define SCAN_BLOCKS 98     // ceil(NN/512)
#define TS 68              // LDS tile stride: 16B-aligned per row, <=2-way bank alias

// ===========================================================================
// CSR build: histogram -> 2-level exclusive scan -> fill. Int atomics only.
// ===========================================================================
__global__ __launch_bounds__(256) void hist_kernel(const int* __restrict__ ei,
                                                   int* __restrict__ counts) {
    const int e = blockIdx.x * blockDim.x + threadIdx.x;
    if (e < EE) atomicAdd(&counts[ei[EE + e]], 1);
}

__global__ __launch_bounds__(512) void scan1_kernel(const int* __restrict__ counts,
                                                    int* __restrict__ scanned,
                                                    int* __restrict__ bsum) {
    __shared__ int buf[512];
    const int i = blockIdx.x * 512 + threadIdx.x;
    const int v = (i < NN) ? counts[i] : 0;
    buf[threadIdx.x] = v;
    __syncthreads();
    for (int off = 1; off < 512; off <<= 1) {
        const int add = (threadIdx.x >= off) ? buf[threadIdx.x - off] : 0;
        __syncthreads();
        buf[threadIdx.x] += add;
        __syncthreads();
    }
    if (i < NN) scanned[i] = buf[threadIdx.x] - v;   // exclusive
    if (threadIdx.x == 511) bsum[blockIdx.x] = buf[511];
}

__global__ __launch_bounds__(512) void scan2_kernel(const int* __restrict__ scanned,
                                                    const int* __restrict__ bsum,
                                                    int* __restrict__ rowptr,
                                                    int* __restrict__ cursor) {
    __shared__ int red[128];
    if (threadIdx.x < 128)
        red[threadIdx.x] = (threadIdx.x < blockIdx.x) ? bsum[threadIdx.x] : 0;
    __syncthreads();
    for (int off = 64; off > 0; off >>= 1) {
        if (threadIdx.x < off) red[threadIdx.x] += red[threadIdx.x + off];
        __syncthreads();
    }
    const int offset = red[0];
    const int i = blockIdx.x * 512 + threadIdx.x;
    if (i < NN) {
        const int p = scanned[i] + offset;
        rowptr[i] = p;
        cursor[i] = p;
    }
    if (blockIdx.x == 0 && threadIdx.x == 0) rowptr[NN] = EE;
}

__global__ __launch_bounds__(256) void fill_kernel(const int* __restrict__ ei,
                                                   int* __restrict__ cursor,
                                                   int* __restrict__ col) {
    const int e = blockIdx.x * blockDim.x + threadIdx.x;
    if (e < EE) {
        const int pos = atomicAdd(&cursor[ei[EE + e]], 1);
        col[pos] = ei[e];
    }
}

// ===========================================================================
// Fused GIN layer: per 64-row tile (one block, 4 waves):
//  phase 0: gather  z = scl.*(h_self + sum_nbr h) + (deg+1).*sft  -> LDS tile
//           (scl/sft = previous layer's folded BN affine; identity on layer 1)
//  phase 1: matmul A + relu -> tile2   (lane = row, wave owns 16 features)
//  phase 2: matmul B + relu -> tile    (t values)
//  phase 3: per-tile BN partial sums; coalesced t writeback
// ===========================================================================
__global__ __launch_bounds__(256) void fused_mlp_kernel(const float* __restrict__ hin,
                                                        const int* __restrict__ rowptr,
                                                        const int* __restrict__ col,
                                                        const float* __restrict__ ss,
                                                        const int apply,
                                                        const float* __restrict__ wa,
                                                        const float* __restrict__ ba,
                                                        const float* __restrict__ wb,
                                                        const float* __restrict__ bb,
                                                        float* __restrict__ t,
                                                        float* __restrict__ partials) {
    __shared__ float tile[64 * TS];
    __shared__ float tile2[64 * TS];
    __shared__ float red[4][128];

    const int wave = threadIdx.x >> 6;
    const int lane = threadIdx.x & 63;
    const int row0 = blockIdx.x * 64;
    const int nrows = min(64, NN - row0);

    // ---- phase 0: gather (lane = feature, wave owns 16 tile rows) ----
    const float scl = apply ? ss[lane] : 1.0f;
    const float sft = apply ? ss[64 + lane] : 0.0f;
    for (int r = wave * 16; r < wave * 16 + 16; ++r) {
        const int row = row0 + r;
        float zv = 0.f;
        if (row < NN) {
            const int beg = rowptr[row];
            const int end = rowptr[row + 1];
            float a0 = hin[row * 64 + lane];  // self term
            float a1 = 0.f, a2 = 0.f, a3 = 0.f, a4 = 0.f, a5 = 0.f, a6 = 0.f, a7 = 0.f;
            int j = beg;
            for (; j + 8 <= end; j += 8) {
                const int s0 = col[j], s1 = col[j + 1], s2 = col[j + 2], s3 = col[j + 3];
                const int s4 = col[j + 4], s5 = col[j + 5], s6 = col[j + 6], s7 = col[j + 7];
                a0 += hin[s0 * 64 + lane];
                a1 += hin[s1 * 64 + lane];
                a2 += hin[s2 * 64 + lane];
                a3 += hin[s3 * 64 + lane];
                a4 += hin[s4 * 64 + lane];
                a5 += hin[s5 * 64 + lane];
                a6 += hin[s6 * 64 + lane];
                a7 += hin[s7 * 64 + lane];
            }
            for (; j < end; ++j) a1 += hin[col[j] * 64 + lane];
            const float sum = ((a0 + a1) + (a2 + a3)) + ((a4 + a5) + (a6 + a7));
            zv = fmaf(sum, scl, (float)(end - beg + 1) * sft);
        }
        tile[r * TS + lane] = zv;
    }
    __syncthreads();

    // ---- phase 1: A-matmul, lane = row, features f0..f0+15 ----
    const int f0 = wave * 16;
    float acc[16];
    #pragma unroll
    for (int j = 0; j < 16; ++j) acc[j] = ba[f0 + j];
    #pragma unroll 4
    for (int k4 = 0; k4 < 16; ++k4) {
        const float4 v = *(const float4*)(&tile[lane * TS + k4 * 4]);
        #pragma unroll
        for (int j = 0; j < 16; ++j) {
            acc[j] = fmaf(v.x, wa[(k4 * 4 + 0) * 64 + f0 + j], acc[j]);
            acc[j] = fmaf(v.y, wa[(k4 * 4 + 1) * 64 + f0 + j], acc[j]);
            acc[j] = fmaf(v.z, wa[(k4 * 4 + 2) * 64 + f0 + j], acc[j]);
            acc[j] = fmaf(v.w, wa[(k4 * 4 + 3) * 64 + f0 + j], acc[j]);
        }
    }
    #pragma unroll
    for (int j = 0; j < 16; j += 4) {
        float4 o;
        o.x = fmaxf(acc[j + 0], 0.f);
        o.y = fmaxf(acc[j + 1], 0.f);
        o.z = fmaxf(acc[j + 2], 0.f);
        o.w = fmaxf(acc[j + 3], 0.f);
        *(float4*)(&tile2[lane * TS + f0 + j]) = o;
    }
    __syncthreads();

    // ---- phase 2: B-matmul -> t values into tile (input tile is dead now) ----
    #pragma unroll
    for (int j = 0; j < 16; ++j) acc[j] = bb[f0 + j];
    #pragma unroll 4
    for (int k4 = 0; k4 < 16; ++k4) {
        const float4 v = *(const float4*)(&tile2[lane * TS + k4 * 4]);
        #pragma unroll
        for (int j = 0; j < 16; ++j) {
            acc[j] = fmaf(v.x, wb[(k4 * 4 + 0) * 64 + f0 + j], acc[j]);
            acc[j] = fmaf(v.y, wb[(k4 * 4 + 1) * 64 + f0 + j], acc[j]);
            acc[j] = fmaf(v.z, wb[(k4 * 4 + 2) * 64 + f0 + j], acc[j]);
            acc[j] = fmaf(v.w, wb[(k4 * 4 + 3) * 64 + f0 + j], acc[j]);
        }
    }
    #pragma unroll
    for (int j = 0; j < 16; j += 4) {
        float4 o;
        o.x = fmaxf(acc[j + 0], 0.f);
        o.y = fmaxf(acc[j + 1], 0.f);
        o.z = fmaxf(acc[j + 2], 0.f);
        o.w = fmaxf(acc[j + 3], 0.f);
        *(float4*)(&tile[lane * TS + f0 + j]) = o;
    }
    __syncthreads();

    // ---- phase 3a: BN partials (lane = feature, wave sums its 16 rows) ----
    {
        const int rbeg = wave * 16;
        const int rend = min(rbeg + 16, nrows);
        float s = 0.f, sq = 0.f;
        for (int r = rbeg; r < rend; ++r) {
            const float v = tile[r * TS + lane];
            s += v;
            sq += v * v;
        }
        red[wave][lane] = s;
        red[wave][64 + lane] = sq;
    }
    __syncthreads();
    if (threadIdx.x < 128)
        partials[blockIdx.x * 128 + threadIdx.x] =
            red[0][threadIdx.x] + red[1][threadIdx.x] +
            red[2][threadIdx.x] + red[3][threadIdx.x];

    // ---- phase 3b: coalesced t writeback ----
    #pragma unroll
    for (int m = 0; m < 4; ++m) {
        const int q = m * 1024 + threadIdx.x * 4;
        const int r = q >> 6, f = q & 63;
        const int grow = row0 + r;
        if (grow < NN)
            *(float4*)(t + grow * 64 + f) = *(const float4*)(&tile[r * TS + f]);
    }
}

// ===========================================================================
// Reduce TILES partial blocks -> fused BN scale/shift
// ===========================================================================
__global__ __launch_bounds__(1024) void finalize_kernel(const float* __restrict__ partials,
                                                        const float* __restrict__ g,
                                                        const float* __restrict__ be,
                                                        float* __restrict__ ss) {
    __shared__ float red[1024];
    const int f = threadIdx.x & 127;
    const int seg = threadIdx.x >> 7;  // 0..7
    float s = 0.f;
    for (int b = seg; b < TILES; b += 8) s += partials[b * 128 + f];
    red[threadIdx.x] = s;
    __syncthreads();
    if (threadIdx.x < 128) {
        float tot = 0.f;
        #pragma unroll
        for (int k = 0; k < 8; ++k) tot += red[k * 128 + threadIdx.x];
        red[threadIdx.x] = tot;
    }
    __syncthreads();
    if (threadIdx.x < 64) {
        const float mean = red[threadIdx.x] * (1.0f / NN);
        const float var = red[64 + threadIdx.x] * (1.0f / NN) - mean * mean;
        const float scl = g[threadIdx.x] * rsqrtf(var + 1e-5f);
        ss[threadIdx.x] = scl;
        ss[64 + threadIdx.x] = be[threadIdx.x] - mean * scl;
    }
}

// ===========================================================================
// Pool with fused layer-3 affine; batch sorted -> boundary-only atomics.
// ===========================================================================
__global__ __launch_bounds__(256) void pool_kernel(const float* __restrict__ t,
                                                   const int* __restrict__ batch,
                                                   const float* __restrict__ ss,
                                                   float* __restrict__ xpool) {
    const int wv = (blockIdx.x * 256 + threadIdx.x) >> 6;
    const int lane = threadIdx.x & 63;
    const int r0 = wv * 64;
    if (r0 >= NN) return;
    const int r1 = min(r0 + 64, NN);
    const float scl = ss[lane];
    const float sft = ss[64 + lane];
    int gprev = batch[r0];
    float acc = 0.f;
    for (int r = r0; r < r1; ++r) {
        const int g = batch[r];
        if (g != gprev) {
            __hip_atomic_fetch_add(&xpool[gprev * 64 + lane], acc,
                                   __ATOMIC_RELAXED, __HIP_MEMORY_SCOPE_AGENT);
            acc = 0.f;
            gprev = g;
        }
        acc += fmaf(t[r * 64 + lane], scl, sft);
    }
    __hip_atomic_fetch_add(&xpool[gprev * 64 + lane], acc,
                           __ATOMIC_RELAXED, __HIP_MEMORY_SCOPE_AGENT);
}

// ===========================================================================
// Head
// ===========================================================================
__global__ __launch_bounds__(256) void lin0_kernel(const float* __restrict__ xpool,
                                                   const float* __restrict__ w,
                                                   const float* __restrict__ b,
                                                   float* __restrict__ mid) {
    const int tid = blockIdx.x * blockDim.x + threadIdx.x;  // GG*128
    if (tid >= GG * 128) return;
    const int g = tid >> 7;
    const int m = tid & 127;
    float acc = b[m];
    #pragma unroll 8
    for (int k = 0; k < 64; ++k) acc = fmaf(xpool[g * 64 + k], w[k * 128 + m], acc);
    mid[tid] = acc;
}

__global__ __launch_bounds__(256) void fc1_kernel(const float* __restrict__ mid,
                                                  const float* __restrict__ w,
                                                  const float* __restrict__ b,
                                                  float* __restrict__ out) {
    const int tid = blockIdx.x * blockDim.x + threadIdx.x;  // GG*64
    if (tid >= GG * 64) return;
    const int g = tid >> 6;
    const int j = tid & 63;
    float acc = b[j];
    #pragma unroll 8
    for (int k = 0; k < 128; ++k) acc = fmaf(mid[g * 128 + k], w[k * 64 + j], acc);
    out[tid] = fmaxf(acc, 0.f);
}

extern "C" void kernel_launch(void* const* d_in, const int* in_sizes, int n_in,
                              void* d_out, int out_size, void* d_ws, size_t ws_size,
                              hipStream_t stream) {
    const float* x = (const float*)d_in[0];
    const int* ei = (const int*)d_in[1];
    const int* batch = (const int*)d_in[2];

    // ---- workspace layout ----
    int* ibase   = (int*)d_ws;
    int* counts  = ibase;            // 50000
    int* scanned = ibase + 50000;    // 50000
    int* rowptr  = ibase + 100000;   // 50001 (pad to 50004)
    int* cursor  = ibase + 150004;   // 50000
    int* bsum    = ibase + 200004;   // 128 (98 used)
    int* col     = ibase + 200132;   // 800000 -> int end 1,000,132 (pad 1,000,192)
    float* fbase = (float*)d_ws + 1000192;  // 16B aligned
    float* t0       = fbase;                // NN*64 = 3,200,000
    float* t1       = t0 + 3200000;         // NN*64
    float* partials = t1 + 3200000;         // TILES*128 = 100,096
    float* ss       = partials + 100096;    // 128
    float* xpool    = ss + 128;             // GG*64 = 32768
    float* mid      = xpool + 32768;        // GG*128 = 65536

    // ---- CSR build (once, reused by all 3 layers) ----
    hipMemsetAsync(counts, 0, 50000 * sizeof(int), stream);
    hist_kernel<<<(EE + 255) / 256, 256, 0, stream>>>(ei, counts);
    scan1_kernel<<<SCAN_BLOCKS, 512, 0, stream>>>(counts, scanned, bsum);
    scan2_kernel<<<SCAN_BLOCKS, 512, 0, stream>>>(scanned, bsum, rowptr, cursor);
    fill_kernel<<<(EE + 255) / 256, 256, 0, stream>>>(ei, cursor, col);

    // ---- 3 fused GIN layers (ping-pong t0/t1: hin==tout would race) ----
    const float* hcur = x;
    float* touts[3] = {t0, t1, t0};
    for (int l = 0; l < 3; ++l) {
        const float* wa = (const float*)d_in[3 + l * 6 + 0];
        const float* ba = (const float*)d_in[3 + l * 6 + 1];
        const float* wb = (const float*)d_in[3 + l * 6 + 2];
        const float* bb = (const float*)d_in[3 + l * 6 + 3];
        const float* ga = (const float*)d_in[3 + l * 6 + 4];
        const float* be = (const float*)d_in[3 + l * 6 + 5];

        fused_mlp_kernel<<<TILES, 256, 0, stream>>>(hcur, rowptr, col, ss, l > 0,
                                                    wa, ba, wb, bb, touts[l], partials);
        finalize_kernel<<<1, 1024, 0, stream>>>(partials, ga, be, ss);
        hcur = touts[l];
    }

    hipMemsetAsync(xpool, 0, (size_t)GG * 64 * sizeof(float), stream);
    pool_kernel<<<(TILES + 3) / 4, 256, 0, stream>>>(t0, batch, ss, xpool);
    lin0_kernel<<<(GG * 128 + 255) / 256, 256, 0, stream>>>(
        xpool, (const float*)d_in[21], (const float*)d_in[22], mid);
    fc1_kernel<<<(GG * 64 + 255) / 256, 256, 0, stream>>>(
        mid, (const float*)d_in[23], (const float*)d_in[24], (float*)d_out);
}

// Round 5
// 597.025 us; speedup vs baseline: 1.1210x; 1.1210x over previous
//
#include <hip/hip_runtime.h>

#define NN 50000
#define EE 800000
#define DD 64
#define GG 512
#define TILES 782          // ceil(NN/64)
#define SCAN_BLOCKS 98     // ceil(NN/512)
#define TS 68              // LDS tile stride: 16B-aligned rows, lane*TS spreads banks

// ---- bf16 helpers (manual, avoids header API drift) ----
__device__ __forceinline__ float b2f(unsigned short u) {
    union { unsigned int i; float f; } c;
    c.i = ((unsigned int)u) << 16;
    return c.f;
}
__device__ __forceinline__ unsigned short f2b(float f) {
    union { float f; unsigned int i; } c;
    c.f = f;
    const unsigned int r = c.i + 0x7FFFu + ((c.i >> 16) & 1u);  // round-nearest-even
    return (unsigned short)(r >> 16);
}

// ===========================================================================
// CSR build: histogram -> 2-level exclusive scan -> fill. Int atomics only.
// ===========================================================================
__global__ __launch_bounds__(256) void hist_kernel(const int* __restrict__ ei,
                                                   int* __restrict__ counts) {
    const int e = blockIdx.x * blockDim.x + threadIdx.x;
    if (e < EE) atomicAdd(&counts[ei[EE + e]], 1);
}

__global__ __launch_bounds__(512) void scan1_kernel(const int* __restrict__ counts,
                                                    int* __restrict__ scanned,
                                                    int* __restrict__ bsum) {
    __shared__ int buf[512];
    const int i = blockIdx.x * 512 + threadIdx.x;
    const int v = (i < NN) ? counts[i] : 0;
    buf[threadIdx.x] = v;
    __syncthreads();
    for (int off = 1; off < 512; off <<= 1) {
        const int add = (threadIdx.x >= off) ? buf[threadIdx.x - off] : 0;
        __syncthreads();
        buf[threadIdx.x] += add;
        __syncthreads();
    }
    if (i < NN) scanned[i] = buf[threadIdx.x] - v;   // exclusive
    if (threadIdx.x == 511) bsum[blockIdx.x] = buf[511];
}

__global__ __launch_bounds__(512) void scan2_kernel(const int* __restrict__ scanned,
                                                    const int* __restrict__ bsum,
                                                    int* __restrict__ rowptr,
                                                    int* __restrict__ cursor) {
    __shared__ int red[128];
    if (threadIdx.x < 128)
        red[threadIdx.x] = (threadIdx.x < blockIdx.x) ? bsum[threadIdx.x] : 0;
    __syncthreads();
    for (int off = 64; off > 0; off >>= 1) {
        if (threadIdx.x < off) red[threadIdx.x] += red[threadIdx.x + off];
        __syncthreads();
    }
    const int offset = red[0];
    const int i = blockIdx.x * 512 + threadIdx.x;
    if (i < NN) {
        const int p = scanned[i] + offset;
        rowptr[i] = p;
        cursor[i] = p;
    }
    if (blockIdx.x == 0 && threadIdx.x == 0) rowptr[NN] = EE;
}

__global__ __launch_bounds__(256) void fill_kernel(const int* __restrict__ ei,
                                                   int* __restrict__ cursor,
                                                   int* __restrict__ col) {
    const int e = blockIdx.x * blockDim.x + threadIdx.x;
    if (e < EE) {
        const int pos = atomicAdd(&cursor[ei[EE + e]], 1);
        col[pos] = ei[e];
    }
}

// ===========================================================================
// fp32 -> bf16 conversion (x staged once)
// ===========================================================================
__global__ __launch_bounds__(256) void tobf_kernel(const float* __restrict__ in,
                                                   unsigned short* __restrict__ out,
                                                   const int n4) {
    const int i = blockIdx.x * 256 + threadIdx.x;
    if (i >= n4) return;
    const float4 v = ((const float4*)in)[i];
    ushort4 o;
    o.x = f2b(v.x); o.y = f2b(v.y); o.z = f2b(v.z); o.w = f2b(v.w);
    ((ushort4*)out)[i] = o;
}

// ===========================================================================
// Fused GIN layer, 64-row tile, 512 threads (8 waves):
//  phase 0: gather (bf16 in, prev-layer BN affine folded) -> fp32 LDS tile
//  phase 1: matmul A + relu -> tile2  (lane = row, wave owns 8 features)
//  phase 2: matmul B + relu -> tile   (raw t values, pre-affine)
//  phase 3: BN partial sums -> 8-slot atomic stats; bf16 t writeback
// ===========================================================================
__global__ __launch_bounds__(512) void fused_mlp_kernel(const unsigned short* __restrict__ hin,
                                                        const int* __restrict__ rowptr,
                                                        const int* __restrict__ col,
                                                        const float* __restrict__ ss,
                                                        const int apply,
                                                        const float* __restrict__ wa,
                                                        const float* __restrict__ ba,
                                                        const float* __restrict__ wb,
                                                        const float* __restrict__ bb,
                                                        unsigned short* __restrict__ tout,
                                                        float* __restrict__ stats) {
    __shared__ float tile[64 * TS];
    __shared__ float tile2[64 * TS];
    __shared__ float red[8][128];

    const int wave = threadIdx.x >> 6;
    const int lane = threadIdx.x & 63;
    const int row0 = blockIdx.x * 64;
    const int nrows = min(64, NN - row0);

    // ---- phase 0: gather; wave owns 8 tile rows, lane = feature ----
    const float scl = apply ? ss[lane] : 1.0f;
    const float sft = apply ? ss[64 + lane] : 0.0f;
    for (int r = wave * 8; r < wave * 8 + 8; ++r) {
        const int row = row0 + r;
        float zv = 0.f;
        if (row < NN) {
            const int beg = rowptr[row];
            const int end = rowptr[row + 1];
            float a0 = b2f(hin[row * 64 + lane]);  // self term
            float a1 = 0.f, a2 = 0.f, a3 = 0.f, a4 = 0.f, a5 = 0.f, a6 = 0.f, a7 = 0.f;
            int j = beg;
            for (; j + 8 <= end; j += 8) {
                const int s0 = col[j], s1 = col[j + 1], s2 = col[j + 2], s3 = col[j + 3];
                const int s4 = col[j + 4], s5 = col[j + 5], s6 = col[j + 6], s7 = col[j + 7];
                a0 += b2f(hin[s0 * 64 + lane]);
                a1 += b2f(hin[s1 * 64 + lane]);
                a2 += b2f(hin[s2 * 64 + lane]);
                a3 += b2f(hin[s3 * 64 + lane]);
                a4 += b2f(hin[s4 * 64 + lane]);
                a5 += b2f(hin[s5 * 64 + lane]);
                a6 += b2f(hin[s6 * 64 + lane]);
                a7 += b2f(hin[s7 * 64 + lane]);
            }
            for (; j < end; ++j) a1 += b2f(hin[col[j] * 64 + lane]);
            const float sum = ((a0 + a1) + (a2 + a3)) + ((a4 + a5) + (a6 + a7));
            zv = fmaf(sum, scl, (float)(end - beg + 1) * sft);
        }
        tile[r * TS + lane] = zv;
    }
    __syncthreads();

    // ---- phase 1: A-matmul, lane = row, wave owns features f0..f0+7 ----
    const int f0 = wave * 8;
    float acc[8];
    #pragma unroll
    for (int j = 0; j < 8; ++j) acc[j] = ba[f0 + j];
    #pragma unroll 4
    for (int k4 = 0; k4 < 16; ++k4) {
        const float4 v = *(const float4*)(&tile[lane * TS + k4 * 4]);
        #pragma unroll
        for (int j = 0; j < 8; ++j) {
            acc[j] = fmaf(v.x, wa[(k4 * 4 + 0) * 64 + f0 + j], acc[j]);
            acc[j] = fmaf(v.y, wa[(k4 * 4 + 1) * 64 + f0 + j], acc[j]);
            acc[j] = fmaf(v.z, wa[(k4 * 4 + 2) * 64 + f0 + j], acc[j]);
            acc[j] = fmaf(v.w, wa[(k4 * 4 + 3) * 64 + f0 + j], acc[j]);
        }
    }
    #pragma unroll
    for (int j = 0; j < 8; j += 4) {
        float4 o;
        o.x = fmaxf(acc[j + 0], 0.f);
        o.y = fmaxf(acc[j + 1], 0.f);
        o.z = fmaxf(acc[j + 2], 0.f);
        o.w = fmaxf(acc[j + 3], 0.f);
        *(float4*)(&tile2[lane * TS + f0 + j]) = o;
    }
    __syncthreads();

    // ---- phase 2: B-matmul -> raw t into tile ----
    #pragma unroll
    for (int j = 0; j < 8; ++j) acc[j] = bb[f0 + j];
    #pragma unroll 4
    for (int k4 = 0; k4 < 16; ++k4) {
        const float4 v = *(const float4*)(&tile2[lane * TS + k4 * 4]);
        #pragma unroll
        for (int j = 0; j < 8; ++j) {
            acc[j] = fmaf(v.x, wb[(k4 * 4 + 0) * 64 + f0 + j], acc[j]);
            acc[j] = fmaf(v.y, wb[(k4 * 4 + 1) * 64 + f0 + j], acc[j]);
            acc[j] = fmaf(v.z, wb[(k4 * 4 + 2) * 64 + f0 + j], acc[j]);
            acc[j] = fmaf(v.w, wb[(k4 * 4 + 3) * 64 + f0 + j], acc[j]);
        }
    }
    #pragma unroll
    for (int j = 0; j < 8; j += 4) {
        float4 o;
        o.x = fmaxf(acc[j + 0], 0.f);
        o.y = fmaxf(acc[j + 1], 0.f);
        o.z = fmaxf(acc[j + 2], 0.f);
        o.w = fmaxf(acc[j + 3], 0.f);
        *(float4*)(&tile[lane * TS + f0 + j]) = o;
    }
    __syncthreads();

    // ---- phase 3a: BN partials (lane = feature, wave sums its 8 rows) ----
    {
        const int rbeg = wave * 8;
        const int rend = min(rbeg + 8, nrows);
        float s = 0.f, sq = 0.f;
        for (int r = rbeg; r < rend; ++r) {
            const float v = tile[r * TS + lane];
            s += v;
            sq += v * v;
        }
        red[wave][lane] = s;
        red[wave][64 + lane] = sq;
    }
    __syncthreads();
    if (threadIdx.x < 128) {
        float tot = 0.f;
        #pragma unroll
        for (int w = 0; w < 8; ++w) tot += red[w][threadIdx.x];
        atomicAdd(&stats[(blockIdx.x & 7) * 128 + threadIdx.x], tot);
    }

    // ---- phase 3b: bf16 t writeback (ushort4 = 4 feats/thread) ----
    #pragma unroll
    for (int m = 0; m < 2; ++m) {
        const int g = m * 512 + threadIdx.x;      // 1024 ushort4 groups
        const int r = g >> 4;
        const int f = (g & 15) * 4;
        const int grow = row0 + r;
        if (grow < NN) {
            const float4 v = *(const float4*)(&tile[r * TS + f]);
            ushort4 o;
            o.x = f2b(v.x); o.y = f2b(v.y); o.z = f2b(v.z); o.w = f2b(v.w);
            *(ushort4*)(tout + grow * 64 + f) = o;
        }
    }
}

// ===========================================================================
// stats[8][128] -> fused BN scale/shift (tiny)
// ===========================================================================
__global__ __launch_bounds__(128) void finalize_kernel(const float* __restrict__ stats,
                                                       const float* __restrict__ g,
                                                       const float* __restrict__ be,
                                                       float* __restrict__ ss) {
    __shared__ float red[128];
    const int f = threadIdx.x;
    float tot = 0.f;
    #pragma unroll
    for (int k = 0; k < 8; ++k) tot += stats[k * 128 + f];
    red[f] = tot;
    __syncthreads();
    if (f < 64) {
        const float mean = red[f] * (1.0f / NN);
        const float var = red[64 + f] * (1.0f / NN) - mean * mean;
        const float scl = g[f] * rsqrtf(var + 1e-5f);
        ss[f] = scl;
        ss[64 + f] = be[f] - mean * scl;
    }
}

// ===========================================================================
// Pool (bf16 t in, layer-3 affine fused); batch sorted -> boundary atomics.
// ===========================================================================
__global__ __launch_bounds__(256) void pool_kernel(const unsigned short* __restrict__ t,
                                                   const int* __restrict__ batch,
                                                   const float* __restrict__ ss,
                                                   float* __restrict__ xpool) {
    const int wv = (blockIdx.x * 256 + threadIdx.x) >> 6;
    const int lane = threadIdx.x & 63;
    const int r0 = wv * 64;
    if (r0 >= NN) return;
    const int r1 = min(r0 + 64, NN);
    const float scl = ss[lane];
    const float sft = ss[64 + lane];
    int gprev = batch[r0];
    float acc = 0.f;
    for (int r = r0; r < r1; ++r) {
        const int g = batch[r];
        if (g != gprev) {
            __hip_atomic_fetch_add(&xpool[gprev * 64 + lane], acc,
                                   __ATOMIC_RELAXED, __HIP_MEMORY_SCOPE_AGENT);
            acc = 0.f;
            gprev = g;
        }
        acc += fmaf(b2f(t[r * 64 + lane]), scl, sft);
    }
    __hip_atomic_fetch_add(&xpool[gprev * 64 + lane], acc,
                           __ATOMIC_RELAXED, __HIP_MEMORY_SCOPE_AGENT);
}

// ===========================================================================
// Head
// ===========================================================================
__global__ __launch_bounds__(256) void lin0_kernel(const float* __restrict__ xpool,
                                                   const float* __restrict__ w,
                                                   const float* __restrict__ b,
                                                   float* __restrict__ mid) {
    const int tid = blockIdx.x * blockDim.x + threadIdx.x;  // GG*128
    if (tid >= GG * 128) return;
    const int g = tid >> 7;
    const int m = tid & 127;
    float acc = b[m];
    #pragma unroll 8
    for (int k = 0; k < 64; ++k) acc = fmaf(xpool[g * 64 + k], w[k * 128 + m], acc);
    mid[tid] = acc;
}

__global__ __launch_bounds__(256) void fc1_kernel(const float* __restrict__ mid,
                                                  const float* __restrict__ w,
                                                  const float* __restrict__ b,
                                                  float* __restrict__ out) {
    const int tid = blockIdx.x * blockDim.x + threadIdx.x;  // GG*64
    if (tid >= GG * 64) return;
    const int g = tid >> 6;
    const int j = tid & 63;
    float acc = b[j];
    #pragma unroll 8
    for (int k = 0; k < 128; ++k) acc = fmaf(mid[g * 128 + k], w[k * 64 + j], acc);
    out[tid] = fmaxf(acc, 0.f);
}

extern "C" void kernel_launch(void* const* d_in, const int* in_sizes, int n_in,
                              void* d_out, int out_size, void* d_ws, size_t ws_size,
                              hipStream_t stream) {
    const float* x = (const float*)d_in[0];
    const int* ei = (const int*)d_in[1];
    const int* batch = (const int*)d_in[2];

    // ---- workspace layout ----
    int* ibase   = (int*)d_ws;
    int* counts  = ibase;            // 50000
    int* scanned = ibase + 50000;    // 50000
    int* rowptr  = ibase + 100000;   // 50001 (pad to 50004)
    int* cursor  = ibase + 150004;   // 50000
    int* bsum    = ibase + 200004;   // 128 (98 used)
    int* col     = ibase + 200132;   // 800000 -> int end 1,000,132 (pad 1,000,192)
    float* fbase = (float*)d_ws + 1000192;       // 16B aligned
    float* stats = fbase;                        // 3 layers x 1024 = 3072
    float* xpool = stats + 3072;                 // 32768 (adjacent: one memset)
    float* ss    = xpool + 32768;                // 128
    float* mid   = ss + 128;                     // 65536
    unsigned short* xbf  = (unsigned short*)(mid + 65536);  // 3.2M ushorts
    unsigned short* t0bf = xbf + 3200000;
    unsigned short* t1bf = t0bf + 3200000;

    // ---- CSR build (once, reused by all 3 layers) + zeroing ----
    hipMemsetAsync(counts, 0, 50000 * sizeof(int), stream);
    hipMemsetAsync(stats, 0, (3072 + 32768) * sizeof(float), stream);  // stats + xpool
    hist_kernel<<<(EE + 255) / 256, 256, 0, stream>>>(ei, counts);
    scan1_kernel<<<SCAN_BLOCKS, 512, 0, stream>>>(counts, scanned, bsum);
    scan2_kernel<<<SCAN_BLOCKS, 512, 0, stream>>>(scanned, bsum, rowptr, cursor);
    fill_kernel<<<(EE + 255) / 256, 256, 0, stream>>>(ei, cursor, col);
    tobf_kernel<<<(800000 + 255) / 256, 256, 0, stream>>>(x, xbf, 800000);

    // ---- 3 fused GIN layers (bf16 ping-pong; hin==tout would race) ----
    const unsigned short* hcur = xbf;
    unsigned short* touts[3] = {t0bf, t1bf, t0bf};
    for (int l = 0; l < 3; ++l) {
        const float* wa = (const float*)d_in[3 + l * 6 + 0];
        const float* ba = (const float*)d_in[3 + l * 6 + 1];
        const float* wb = (const float*)d_in[3 + l * 6 + 2];
        const float* bb = (const float*)d_in[3 + l * 6 + 3];
        const float* ga = (const float*)d_in[3 + l * 6 + 4];
        const float* be = (const float*)d_in[3 + l * 6 + 5];

        fused_mlp_kernel<<<TILES, 512, 0, stream>>>(hcur, rowptr, col, ss, l > 0,
                                                    wa, ba, wb, bb, touts[l],
                                                    stats + l * 1024);
        finalize_kernel<<<1, 128, 0, stream>>>(stats + l * 1024, ga, be, ss);
        hcur = touts[l];
    }

    pool_kernel<<<(TILES + 3) / 4, 256, 0, stream>>>(t0bf, batch, ss, xpool);
    lin0_kernel<<<(GG * 128 + 255) / 256, 256, 0, stream>>>(
        xpool, (const float*)d_in[21], (const float*)d_in[22], mid);
    fc1_kernel<<<(GG * 64 + 255) / 256, 256, 0, stream>>>(
        mid, (const float*)d_in[23], (const float*)d_in[24], (float*)d_out);
}